// Round 1
// baseline (284.445 us; speedup 1.0000x reference)
//
#include <hip/hip_runtime.h>
#include <hip/hip_bf16.h>

#define NL 6
#define DT 6144
#define DM 768
#define TOK 128

using bf16x8 = __attribute__((ext_vector_type(8))) short;
using f32x4  = __attribute__((ext_vector_type(4))) float;

// round-to-nearest-even f32 -> bf16 (branchless; inputs are finite)
__device__ __forceinline__ short f2bf(float f) {
  union { float f; unsigned u; } c; c.f = f;
  unsigned u = c.u;
  u += 0x7fffu + ((u >> 16) & 1u);
  return (short)(u >> 16);
}

__device__ __forceinline__ bf16x8 cvt8(float4 v0, float4 v1) {
  bf16x8 r;
  r[0] = f2bf(v0.x); r[1] = f2bf(v0.y); r[2] = f2bf(v0.z); r[3] = f2bf(v0.w);
  r[4] = f2bf(v1.x); r[5] = f2bf(v1.y); r[6] = f2bf(v1.z); r[7] = f2bf(v1.w);
  return r;
}

// out[j][n][d] = b_dec[j][d]
__global__ void init_k(const float* __restrict__ b_dec, float* __restrict__ out) {
  int idx = blockIdx.x * 256 + threadIdx.x;
  if (idx < NL * TOK * DM) {
    out[idx] = b_dec[(idx / (TOK * DM)) * DM + (idx % DM)];
  }
}

// acts[l][n][f] = relu(x[l] @ W_enc[l]^T + b_enc[l]), bf16 output
// grid: 6 layers * 48 f-tiles of 128; block 256 thr (4 waves, each wave 32 feats)
__global__ __launch_bounds__(256) void encode_k(
    const float* __restrict__ x, const float* __restrict__ W_enc,
    const float* __restrict__ b_enc, ushort* __restrict__ acts)
{
  const int l    = blockIdx.x / (DT / 128);
  const int f0   = (blockIdx.x % (DT / 128)) * 128;
  const int wave = threadIdx.x >> 6;
  const int lane = threadIdx.x & 63;
  const int lo = lane & 15, hi = lane >> 4;
  const int fw = f0 + wave * 32;

  const float* xl = x + (size_t)l * TOK * DM;
  const float* We = W_enc + (size_t)l * DT * DM;

  f32x4 acc[8][2];
  #pragma unroll
  for (int mi = 0; mi < 8; ++mi)
    #pragma unroll
    for (int ni = 0; ni < 2; ++ni)
      acc[mi][ni] = f32x4{0.f, 0.f, 0.f, 0.f};

  for (int d0 = 0; d0 < DM; d0 += 32) {
    const int ka = d0 + hi * 8;
    bf16x8 a[8], b[2];
    #pragma unroll
    for (int mi = 0; mi < 8; ++mi) {
      const float* p = xl + (size_t)(mi * 16 + lo) * DM + ka;
      a[mi] = cvt8(*(const float4*)p, *(const float4*)(p + 4));
    }
    #pragma unroll
    for (int ni = 0; ni < 2; ++ni) {
      const float* p = We + (size_t)(fw + ni * 16 + lo) * DM + ka;
      b[ni] = cvt8(*(const float4*)p, *(const float4*)(p + 4));
    }
    #pragma unroll
    for (int mi = 0; mi < 8; ++mi)
      #pragma unroll
      for (int ni = 0; ni < 2; ++ni)
        acc[mi][ni] = __builtin_amdgcn_mfma_f32_16x16x32_bf16(a[mi], b[ni], acc[mi][ni], 0, 0, 0);
  }

  #pragma unroll
  for (int ni = 0; ni < 2; ++ni) {
    const int f = fw + ni * 16 + lo;
    const float bias = b_enc[l * DT + f];
    #pragma unroll
    for (int mi = 0; mi < 8; ++mi) {
      #pragma unroll
      for (int r = 0; r < 4; ++r) {
        const int n = mi * 16 + hi * 4 + r;
        float v = acc[mi][ni][r] + bias;
        v = v > 0.f ? v : 0.f;
        acts[((size_t)l * TOK + n) * DT + f] = (ushort)f2bf(v);
      }
    }
  }
}

// pair enumeration (i <= j), 21 valid decoder blocks
__device__ const int PI_[21] = {0,0,0,0,0,0, 1,1,1,1,1, 2,2,2,2, 3,3,3, 4,4, 5};
__device__ const int PJ_[21] = {0,1,2,3,4,5, 1,2,3,4,5, 2,3,4,5, 3,4,5, 4,5, 5};

// out[j] += acts[i] @ W_dec[i][j] ; block = (pair, d-tile of 128, f-chunk of 1536)
// grid: 21 * 6 * 4 = 504 blocks; 256 thr (4 waves, each wave 32 d-cols)
__global__ __launch_bounds__(256) void decode_k(
    const ushort* __restrict__ acts, const float* __restrict__ W_dec,
    float* __restrict__ out)
{
  const int bid = blockIdx.x;
  const int p = bid / 24;
  const int t = (bid % 24) / 4;
  const int c = bid % 4;
  const int i = PI_[p], j = PJ_[p];
  const int wave = threadIdx.x >> 6;
  const int lane = threadIdx.x & 63;
  const int lo = lane & 15, hi = lane >> 4;
  const int dw = t * 128 + wave * 32;
  const int fb = c * (DT / 4);

  const ushort* A = acts + (size_t)i * TOK * DT;
  const float*  W = W_dec + (size_t)(i * NL + j) * DT * DM;

  f32x4 acc[8][2];
  #pragma unroll
  for (int mi = 0; mi < 8; ++mi)
    #pragma unroll
    for (int ni = 0; ni < 2; ++ni)
      acc[mi][ni] = f32x4{0.f, 0.f, 0.f, 0.f};

  for (int kk = 0; kk < DT / 4; kk += 32) {
    const int k0 = fb + kk + hi * 8;
    bf16x8 a[8], b[2];
    #pragma unroll
    for (int mi = 0; mi < 8; ++mi)
      a[mi] = *(const bf16x8*)(A + (size_t)(mi * 16 + lo) * DT + k0);
    #pragma unroll
    for (int ni = 0; ni < 2; ++ni) {
      const float* p8 = W + (size_t)k0 * DM + dw + ni * 16 + lo;
      float t0[8];
      #pragma unroll
      for (int e = 0; e < 8; ++e) t0[e] = p8[(size_t)e * DM];
      bf16x8 bb;
      #pragma unroll
      for (int e = 0; e < 8; ++e) bb[e] = f2bf(t0[e]);
      b[ni] = bb;
    }
    #pragma unroll
    for (int mi = 0; mi < 8; ++mi)
      #pragma unroll
      for (int ni = 0; ni < 2; ++ni)
        acc[mi][ni] = __builtin_amdgcn_mfma_f32_16x16x32_bf16(a[mi], b[ni], acc[mi][ni], 0, 0, 0);
  }

  #pragma unroll
  for (int ni = 0; ni < 2; ++ni) {
    const int d = dw + ni * 16 + lo;
    #pragma unroll
    for (int mi = 0; mi < 8; ++mi)
      #pragma unroll
      for (int r = 0; r < 4; ++r) {
        const int n = mi * 16 + hi * 4 + r;
        atomicAdd(out + ((size_t)j * TOK + n) * DM + d, acc[mi][ni][r]);
      }
  }
}

extern "C" void kernel_launch(void* const* d_in, const int* in_sizes, int n_in,
                              void* d_out, int out_size, void* d_ws, size_t ws_size,
                              hipStream_t stream) {
  const float* x     = (const float*)d_in[0];
  const float* W_enc = (const float*)d_in[1];
  const float* b_enc = (const float*)d_in[2];
  const float* b_dec = (const float*)d_in[3];
  const float* W_dec = (const float*)d_in[4];
  float* out = (float*)d_out;
  ushort* acts = (ushort*)d_ws;   // 6*128*6144 bf16 = 9.4 MB

  init_k<<<dim3((NL * TOK * DM + 255) / 256), dim3(256), 0, stream>>>(b_dec, out);
  encode_k<<<dim3(NL * (DT / 128)), dim3(256), 0, stream>>>(x, W_enc, b_enc, acts);
  decode_k<<<dim3(21 * 6 * 4), dim3(256), 0, stream>>>(acts, W_dec, out);
}